// Round 3
// baseline (11590.439 us; speedup 1.0000x reference)
//
#include <hip/hip_runtime.h>
#include <math.h>

typedef _Float16 f16;
typedef _Float16 f16x8 __attribute__((ext_vector_type(8)));
typedef _Float16 f16x4 __attribute__((ext_vector_type(4)));
typedef _Float16 f16x2 __attribute__((ext_vector_type(2)));
typedef float f32x4 __attribute__((ext_vector_type(4)));
typedef unsigned long long u64;

#define B_ 32
#define T_ 1024
#define I_ 128
#define H_ 512

#define NWG 32
#define THR 512

// workspace layout (bytes)
#define OFF_H1C   0UL                   // u64 [2][8192]  = 131072  (epoch-tagged h1 mailbox)
#define OFF_H2C   131072UL              // u64 [2][8192]  = 131072  (epoch-tagged h2 mailbox)
#define OFF_XT    262144UL              // f16 [1024][32][128] = 8,388,608
#define OFF_H2S   8650752UL             // f16 [32][1024][512] = 33,554,432 (b-major for FC1)
#define OFF_O1    42205184UL            // f32 [32768][128]    = 16,777,216
// total: 58,982,400 bytes

#define TAGOF(v) ((unsigned)((v) >> 32))

__device__ inline f32x4 mfma16(f16x8 a, f16x8 b, f32x4 c) {
  return __builtin_amdgcn_mfma_f32_16x16x32_f16(a, b, c, 0, 0, 0);
}
__device__ inline float fast_sig(float x) { return 1.f / (1.f + __expf(-x)); }
__device__ inline float fast_tanh(float x) {
  float e = __expf(-2.f * fabsf(x));
  float t = (1.f - e) / (1.f + e);
  return x < 0.f ? -t : t;
}

// 8B device-coherent mailbox ops (single-transaction, tag+data atomic by alignment)
__device__ inline u64 ld_tag64(const u64* p) {
  u64 r;
  asm volatile("global_load_dwordx2 %0, %1, off sc1" : "=v"(r) : "v"(p) : "memory");
  return r;
}
__device__ inline void st_tag64(u64* p, u64 v) {
  asm volatile("global_store_dwordx2 %0, %1, off sc1" :: "v"(p), "v"(v) : "memory");
}
__device__ inline void wait_vm0() {
  asm volatile("s_waitcnt vmcnt(0)" ::: "memory");
  __builtin_amdgcn_sched_barrier(0);
}

// LDS XOR-swizzle: h rows are 1024B; spread 16B slots across bank groups
__device__ inline int swz_h(int b, int kbyte) { return b * 1024 + (kbyte ^ ((b & 7) << 4)); }
__device__ inline int swz_x(int b, int kbyte) { return b * 256  + (kbyte ^ ((b & 7) << 4)); }

// x[b][t][i] f32 -> xT[t][b][i] f16
__global__ __launch_bounds__(256) void prep_xT(const float* __restrict__ x, f16* __restrict__ xT) {
  const int idx = blockIdx.x * 256 + threadIdx.x;
  const int n4 = B_ * T_ * I_ / 4;
  if (idx < n4) {
    const int i4 = idx * 4;
    const int i  = i4 & (I_ - 1);
    const int tt = (i4 >> 7) & (T_ - 1);
    const int b  = i4 >> 17;
    float4 v = *(const float4*)(x + i4);
    f16x4 o;
    o[0] = (f16)v.x; o[1] = (f16)v.y; o[2] = (f16)v.z; o[3] = (f16)v.w;
    *(f16x4*)(xT + ((size_t)tt * B_ + b) * I_ + i) = o;
  }
}

// Persistent merged 2-layer LSTM with epoch-tagged dataflow exchange (no barrier).
// Step s: L0 computes h1[s] (s<T), L1 computes h2[s-1] (s>=1); both consume h1[s-1].
// Mailbox word (b, pair p): {epoch:u32 | f16x2}. h1[t] -> slot t&1, tag t+1.
// h2[t] -> slot t&1, tag t+1. Step s polls h1 tag s (slot (s+1)&1), h2 tag s-1 (slot s&1).
__global__ __launch_bounds__(THR, 2) void lstm_persist(
    const float* __restrict__ Wih0, const float* __restrict__ Whh0,
    const float* __restrict__ bih0, const float* __restrict__ bhh0,
    const float* __restrict__ Wih1, const float* __restrict__ Whh1,
    const float* __restrict__ bih1, const float* __restrict__ bhh1,
    const f16* __restrict__ xT, u64* h1cur, u64* h2cur, f16* h2seq) {
  __shared__ int4 h1l4[2048];          // 32KB  h1[s-1] (swizzled)
  __shared__ int4 h2l4[2048];          // 32KB  h2[s-2] (swizzled)
  __shared__ int4 xl4[512];            // 8KB   x[s] (swizzled)
  __shared__ float g0[2 * 32 * 68];
  __shared__ float g1[2 * 32 * 68];
  __shared__ float bias0[64], bias1[64];

  const int tid  = threadIdx.x;
  const int wg   = blockIdx.x;
  const int lane = tid & 63;
  const int wv   = tid >> 6;
  const int nt   = wv & 3;
  const int kh   = wv >> 2;
  const int cfr  = lane & 15;
  const int ksub = lane >> 4;

  if (tid < 64) {
    const int g = tid >> 4, hc = tid & 15;
    const int row = g * 512 + wg * 16 + hc;
    bias0[tid] = bih0[row] + bhh0[row];
    bias1[tid] = bih1[row] + bhh1[row];
  }

  // ---- weight preload into VGPRs ----
  const int gc  = nt * 16 + cfr;
  const int row = (gc >> 4) * 512 + wg * 16 + (gc & 15);
  f16x8 wa[10];
#pragma unroll
  for (int ksl = 0; ksl < 10; ++ksl) {
    const int k = (kh * 10 + ksl) * 32 + ksub * 8;
    const float* src = (k < I_) ? (Wih0 + (size_t)row * I_ + k)
                                : (Whh0 + (size_t)row * H_ + (k - I_));
    float4 v0 = *(const float4*)(src);
    float4 v1 = *(const float4*)(src + 4);
    f16x8 h;
    h[0] = (f16)v0.x; h[1] = (f16)v0.y; h[2] = (f16)v0.z; h[3] = (f16)v0.w;
    h[4] = (f16)v1.x; h[5] = (f16)v1.y; h[6] = (f16)v1.z; h[7] = (f16)v1.w;
    wa[ksl] = h;
  }
  f16x8 wb[16];
#pragma unroll
  for (int ksl = 0; ksl < 16; ++ksl) {
    const int k = (kh * 16 + ksl) * 32 + ksub * 8;
    const float* src = (k < H_) ? (Wih1 + (size_t)row * H_ + k)
                                : (Whh1 + (size_t)row * H_ + (k - H_));
    float4 v0 = *(const float4*)(src);
    float4 v1 = *(const float4*)(src + 4);
    f16x8 h;
    h[0] = (f16)v0.x; h[1] = (f16)v0.y; h[2] = (f16)v0.z; h[3] = (f16)v0.w;
    h[4] = (f16)v1.x; h[5] = (f16)v1.y; h[6] = (f16)v1.z; h[7] = (f16)v1.w;
    wb[ksl] = h;
  }

  float cst0 = 0.f, cst1 = 0.f;
  float dst0 = 0.f, dst1 = 0.f;
  const char* h1c = (const char*)h1l4;
  const char* h2c = (const char*)h2l4;
  const char* xc  = (const char*)xl4;

  __syncthreads();

  for (int s = 0; s <= T_; ++s) {
    // ---- exchange phase: batched tag-polls, one vmcnt round trip ----
    const bool hasx  = (s < T_);
    const bool hash2 = (s >= 1);
    int4 xv;
    if (hasx) xv = ((const int4*)(xT + (size_t)s * (B_ * I_)))[tid];

    const u64* h1src = h1cur + (size_t)((s + 1) & 1) * 8192;
    const u64* h2src = h2cur + (size_t)(s & 1) * 8192;
    const unsigned tg1 = (unsigned)s;
    const unsigned tg2 = (unsigned)(s - 1);

    u64 v1[16], v2[16];
#pragma unroll
    for (int j = 0; j < 16; ++j)
      v1[j] = ld_tag64(h1src + ((((j + wg) & 15) << 9) | tid));
    if (hash2) {
#pragma unroll
      for (int j = 0; j < 16; ++j)
        v2[j] = ld_tag64(h2src + ((((j + wg + 7) & 15) << 9) | tid));
    }
    for (;;) {
      wait_vm0();
      bool all = true;
      bool o1_[16], o2_[16];
#pragma unroll
      for (int j = 0; j < 16; ++j) { o1_[j] = (TAGOF(v1[j]) == tg1); all &= o1_[j]; }
#pragma unroll
      for (int j = 0; j < 16; ++j) {
        o2_[j] = !hash2 || (TAGOF(v2[j]) == tg2);
        all &= o2_[j];
      }
      if (all) break;
#pragma unroll
      for (int j = 0; j < 16; ++j)
        if (!o1_[j]) v1[j] = ld_tag64(h1src + ((((j + wg) & 15) << 9) | tid));
#pragma unroll
      for (int j = 0; j < 16; ++j)
        if (!o2_[j]) v2[j] = ld_tag64(h2src + ((((j + wg + 7) & 15) << 9) | tid));
    }
    // payload -> swizzled LDS (4B writes, 2-way banks)
#pragma unroll
    for (int j = 0; j < 16; ++j) {
      const int wi = (((j + wg) & 15) << 9) | tid;
      const int b = wi >> 8, p = wi & 255;
      *(unsigned*)((char*)h1l4 + (b * 1024 + ((p * 4) ^ ((b & 7) << 4)))) = (unsigned)v1[j];
    }
    if (hash2) {
#pragma unroll
      for (int j = 0; j < 16; ++j) {
        const int wi = (((j + wg + 7) & 15) << 9) | tid;
        const int b = wi >> 8, p = wi & 255;
        *(unsigned*)((char*)h2l4 + (b * 1024 + ((p * 4) ^ ((b & 7) << 4)))) = (unsigned)v2[j];
      }
    }
    if (hasx) *(int4*)((char*)xl4 + swz_x(tid >> 4, (tid & 15) * 16)) = xv;
    __syncthreads();

    // ---- MFMA phase (weights in VGPRs, A from LDS) ----
    if (s < T_) {                      // L0: h1[s] gates
      f32x4 a0 = {0.f, 0.f, 0.f, 0.f}, a1 = {0.f, 0.f, 0.f, 0.f};
#pragma unroll
      for (int ksl = 0; ksl < 10; ++ksl) {
        const int k = (kh * 10 + ksl) * 32 + ksub * 8;
        f16x8 af0, af1;
        if (k < I_) {
          af0 = *(const f16x8*)(xc + swz_x(cfr,      k * 2));
          af1 = *(const f16x8*)(xc + swz_x(16 + cfr, k * 2));
        } else {
          af0 = *(const f16x8*)(h1c + swz_h(cfr,      (k - I_) * 2));
          af1 = *(const f16x8*)(h1c + swz_h(16 + cfr, (k - I_) * 2));
        }
        a0 = mfma16(af0, wa[ksl], a0);
        a1 = mfma16(af1, wa[ksl], a1);
      }
      const int base = kh * 2176 + (ksub * 4) * 68 + nt * 16 + cfr;
#pragma unroll
      for (int r = 0; r < 4; ++r) {
        g0[base + r * 68]            = a0[r];
        g0[base + 16 * 68 + r * 68]  = a1[r];
      }
    }
    if (s >= 1) {                      // L1: h2[s-1] gates, input [h1[s-1] | h2[s-2]]
      f32x4 a0 = {0.f, 0.f, 0.f, 0.f}, a1 = {0.f, 0.f, 0.f, 0.f};
#pragma unroll
      for (int ksl = 0; ksl < 16; ++ksl) {
        const int k = (kh * 16 + ksl) * 32 + ksub * 8;
        f16x8 af0, af1;
        if (k < H_) {
          af0 = *(const f16x8*)(h1c + swz_h(cfr,      k * 2));
          af1 = *(const f16x8*)(h1c + swz_h(16 + cfr, k * 2));
        } else {
          af0 = *(const f16x8*)(h2c + swz_h(cfr,      (k - H_) * 2));
          af1 = *(const f16x8*)(h2c + swz_h(16 + cfr, (k - H_) * 2));
        }
        a0 = mfma16(af0, wb[ksl], a0);
        a1 = mfma16(af1, wb[ksl], a1);
      }
      const int base = kh * 2176 + (ksub * 4) * 68 + nt * 16 + cfr;
#pragma unroll
      for (int r = 0; r < 4; ++r) {
        g1[base + r * 68]            = a0[r];
        g1[base + 16 * 68 + r * 68]  = a1[r];
      }
    }
    __syncthreads();

    // ---- pointwise + tagged mailbox store ----
    if (s < T_ && tid < 256) {         // L0 -> h1[s], slot s&1, tag s+1
      const int rb = tid >> 3, hp = tid & 7;
      const float* gr = g0 + rb * 68;
      float hv[2];
#pragma unroll
      for (int cc = 0; cc < 2; ++cc) {
        const int c = 2 * hp + cc;
        const float pi = gr[c]      + gr[2176 + c]      + bias0[c];
        const float pf = gr[16 + c] + gr[2176 + 16 + c] + bias0[16 + c];
        const float pg = gr[32 + c] + gr[2176 + 32 + c] + bias0[32 + c];
        const float po = gr[48 + c] + gr[2176 + 48 + c] + bias0[48 + c];
        const float ig = fast_sig(pi), fg = fast_sig(pf);
        const float gg = fast_tanh(pg), og = fast_sig(po);
        const float cprev = cc ? cst1 : cst0;
        const float cnew = fg * cprev + ig * gg;
        if (cc) cst1 = cnew; else cst0 = cnew;
        hv[cc] = og * fast_tanh(cnew);
      }
      f16x2 pk; pk[0] = (f16)hv[0]; pk[1] = (f16)hv[1];
      const u64 w = ((u64)(unsigned)(s + 1) << 32) | (u64)__builtin_bit_cast(unsigned, pk);
      st_tag64(h1cur + (size_t)(s & 1) * 8192 + (rb * 256 + wg * 8 + hp), w);
    }
    if (s >= 1 && tid >= 256) {        // L1 -> h2[s-1], slot (s-1)&1, tag s
      const int t2 = tid - 256;
      const int rb = t2 >> 3, hp = t2 & 7;
      const float* gr = g1 + rb * 68;
      float hv[2];
#pragma unroll
      for (int cc = 0; cc < 2; ++cc) {
        const int c = 2 * hp + cc;
        const float pi = gr[c]      + gr[2176 + c]      + bias1[c];
        const float pf = gr[16 + c] + gr[2176 + 16 + c] + bias1[16 + c];
        const float pg = gr[32 + c] + gr[2176 + 32 + c] + bias1[32 + c];
        const float po = gr[48 + c] + gr[2176 + 48 + c] + bias1[48 + c];
        const float ig = fast_sig(pi), fg = fast_sig(pf);
        const float gg = fast_tanh(pg), og = fast_sig(po);
        const float cprev = cc ? dst1 : dst0;
        const float cnew = fg * cprev + ig * gg;
        if (cc) dst1 = cnew; else dst0 = cnew;
        hv[cc] = og * fast_tanh(cnew);
      }
      f16x2 pk; pk[0] = (f16)hv[0]; pk[1] = (f16)hv[1];
      const unsigned d = __builtin_bit_cast(unsigned, pk);
      const u64 w = ((u64)(unsigned)s << 32) | (u64)d;
      st_tag64(h2cur + (size_t)((s - 1) & 1) * 8192 + (rb * 256 + wg * 8 + hp), w);
      // full sequence for FC1, b-major [b][t][c]
      __builtin_nontemporal_store(d,
          (unsigned*)(h2seq + ((size_t)rb * T_ + (s - 1)) * H_ + wg * 16 + 2 * hp));
    }
    __syncthreads();                   // protect LDS h tiles until everyone's MFMA reads done
  }
}

// o1[bt][128] = h2seq(f16,[b][t][c])[bt][:] @ fcW^T + fcb   (K=512)
__global__ __launch_bounds__(256) void fc1_kernel(const f16* __restrict__ h2s,
                                                  const float* __restrict__ fcW,
                                                  const float* __restrict__ fcb,
                                                  float* __restrict__ o1) {
  __shared__ float hT[64][36];
  __shared__ float wT[128][36];
  const int bt0 = blockIdx.x * 64;
  const int t = threadIdx.x;
  const int c4 = (t & 31) * 4;
  const int rowg = t >> 5;
  float acc[8][4];
#pragma unroll
  for (int r = 0; r < 8; ++r)
#pragma unroll
    for (int j = 0; j < 4; ++j) acc[r][j] = 0.f;

  for (int kc = 0; kc < 16; ++kc) {
    {
      const int r = t >> 2, q = t & 3;
      const f16x8 v = *(const f16x8*)(h2s + (size_t)(bt0 + r) * 512 + kc * 32 + q * 8);
#pragma unroll
      for (int j = 0; j < 8; ++j) hT[r][q * 8 + j] = (float)v[j];
    }
#pragma unroll
    for (int u = t; u < 1024; u += 256) {
      const int cc = u >> 3, k4 = u & 7;
      *(float4*)&wT[cc][k4 * 4] = *(const float4*)(fcW + (size_t)cc * 512 + kc * 32 + k4 * 4);
    }
    __syncthreads();
#pragma unroll
    for (int k4 = 0; k4 < 8; ++k4) {
      float4 w0 = *(float4*)&wT[c4 + 0][k4 * 4];
      float4 w1 = *(float4*)&wT[c4 + 1][k4 * 4];
      float4 w2 = *(float4*)&wT[c4 + 2][k4 * 4];
      float4 w3 = *(float4*)&wT[c4 + 3][k4 * 4];
#pragma unroll
      for (int rr = 0; rr < 8; ++rr) {
        float4 h = *(float4*)&hT[rowg * 8 + rr][k4 * 4];
        acc[rr][0] += h.x * w0.x + h.y * w0.y + h.z * w0.z + h.w * w0.w;
        acc[rr][1] += h.x * w1.x + h.y * w1.y + h.z * w1.z + h.w * w1.w;
        acc[rr][2] += h.x * w2.x + h.y * w2.y + h.z * w2.z + h.w * w2.w;
        acc[rr][3] += h.x * w3.x + h.y * w3.y + h.z * w3.z + h.w * w3.w;
      }
    }
    __syncthreads();
  }
#pragma unroll
  for (int rr = 0; rr < 8; ++rr) {
    const int r = bt0 + rowg * 8 + rr;
#pragma unroll
    for (int j = 0; j < 4; ++j)
      o1[(size_t)r * 128 + c4 + j] = acc[rr][j] + fcb[c4 + j];
  }
}

// out[bt][128] = o1[bt][:] @ fc2W^T + fc2b   (K=128)
__global__ __launch_bounds__(256) void fc2_kernel(const float* __restrict__ o1,
                                                  const float* __restrict__ fc2W,
                                                  const float* __restrict__ fc2b,
                                                  float* __restrict__ out) {
  __shared__ float oL[64][136];
  const int bt0 = blockIdx.x * 64;
  const int t = threadIdx.x;
#pragma unroll
  for (int u = t; u < 2048; u += 256) {
    const int r = u >> 5, k4 = u & 31;
    *(float4*)&oL[r][k4 * 4] = *(const float4*)(o1 + (size_t)(bt0 + r) * 128 + k4 * 4);
  }
  __syncthreads();
  const int c4 = (t & 31) * 4;
  const int rowg = t >> 5;
  float acc[8][4];
#pragma unroll
  for (int r = 0; r < 8; ++r)
#pragma unroll
    for (int j = 0; j < 4; ++j) acc[r][j] = 0.f;
#pragma unroll
  for (int k4 = 0; k4 < 32; ++k4) {
    float4 w0 = *(const float4*)(fc2W + (size_t)(c4 + 0) * 128 + k4 * 4);
    float4 w1 = *(const float4*)(fc2W + (size_t)(c4 + 1) * 128 + k4 * 4);
    float4 w2 = *(const float4*)(fc2W + (size_t)(c4 + 2) * 128 + k4 * 4);
    float4 w3 = *(const float4*)(fc2W + (size_t)(c4 + 3) * 128 + k4 * 4);
#pragma unroll
    for (int rr = 0; rr < 8; ++rr) {
      float4 h = *(float4*)&oL[rowg * 8 + rr][k4 * 4];
      acc[rr][0] += h.x * w0.x + h.y * w0.y + h.z * w0.z + h.w * w0.w;
      acc[rr][1] += h.x * w1.x + h.y * w1.y + h.z * w1.z + h.w * w1.w;
      acc[rr][2] += h.x * w2.x + h.y * w2.y + h.z * w2.z + h.w * w2.w;
      acc[rr][3] += h.x * w3.x + h.y * w3.y + h.z * w3.z + h.w * w3.w;
    }
  }
#pragma unroll
  for (int rr = 0; rr < 8; ++rr) {
    const int r = bt0 + rowg * 8 + rr;
#pragma unroll
    for (int j = 0; j < 4; ++j)
      out[(size_t)r * 128 + c4 + j] = acc[rr][j] + fc2b[c4 + j];
  }
}

extern "C" void kernel_launch(void* const* d_in, const int* in_sizes, int n_in,
                              void* d_out, int out_size, void* d_ws, size_t ws_size,
                              hipStream_t stream) {
  (void)in_sizes; (void)n_in; (void)out_size; (void)ws_size;
  const float* x    = (const float*)d_in[0];
  const float* Wih0 = (const float*)d_in[1];
  const float* Whh0 = (const float*)d_in[2];
  const float* bih0 = (const float*)d_in[3];
  const float* bhh0 = (const float*)d_in[4];
  const float* Wih1 = (const float*)d_in[5];
  const float* Whh1 = (const float*)d_in[6];
  const float* bih1 = (const float*)d_in[7];
  const float* bhh1 = (const float*)d_in[8];
  const float* fcW  = (const float*)d_in[9];
  const float* fcb  = (const float*)d_in[10];
  const float* fc2W = (const float*)d_in[11];
  const float* fc2b = (const float*)d_in[12];

  char* ws = (char*)d_ws;
  u64* h1cur = (u64*)(ws + OFF_H1C);
  u64* h2cur = (u64*)(ws + OFF_H2C);
  f16* xT    = (f16*)(ws + OFF_XT);
  f16* h2s   = (f16*)(ws + OFF_H2S);
  float* o1  = (float*)(ws + OFF_O1);
  float* out = (float*)d_out;

  // per-call init: mailboxes tag=0 data=0 (== h[-1]=0, h[-2] never matched)
  hipMemsetAsync(ws, 0, 262144, stream);

  prep_xT<<<4096, 256, 0, stream>>>(x, xT);
  lstm_persist<<<NWG, THR, 0, stream>>>(Wih0, Whh0, bih0, bhh0,
                                        Wih1, Whh1, bih1, bhh1,
                                        xT, h1cur, h2cur, h2s);
  fc1_kernel<<<512, 256, 0, stream>>>(h2s, fcW, fcb, o1);
  fc2_kernel<<<512, 256, 0, stream>>>(o1, fc2W, fc2b, out);
}